// Round 5
// baseline (227.770 us; speedup 1.0000x reference)
//
#include <hip/hip_runtime.h>
#include <math.h>

#define N_RES 512
#define NPROJ 1152
#define LSTR  520

#define GLOAD_LDS16(g, l) __builtin_amdgcn_global_load_lds( \
    (const __attribute__((address_space(1))) void*)(g), \
    (__attribute__((address_space(3))) void*)(l), 16, 0, 0)

// ---------------------------------------------------------------------------
// k_wcat: concatenate projection weights into Wcat[384][1152] + bcat[1152].
// ---------------------------------------------------------------------------
__global__ __launch_bounds__(256) void k_wcat(
    const float* __restrict__ Wq,  const float* __restrict__ bq,
    const float* __restrict__ Wkv, const float* __restrict__ bkv,
    const float* __restrict__ Wqp, const float* __restrict__ bqp,
    const float* __restrict__ Wkvp,const float* __restrict__ bkvp,
    float* __restrict__ wcat)   // 442368 weights + 1152 bias
{
    const int idx = blockIdx.x * 256 + threadIdx.x;
    if (idx < 442368) {
        const int k = idx / 1152, col = idx % 1152;
        float v;
        if (col < 192)      v = Wq  [(size_t)k*192 + col];
        else if (col < 576) v = Wkv [(size_t)k*384 + col-192];
        else if (col < 720) v = Wqp [(size_t)k*144 + col-576];
        else                v = Wkvp[(size_t)k*432 + col-720];
        wcat[idx] = v;
    } else if (idx < 443520) {
        const int col = idx - 442368;
        float v;
        if (col < 192)      v = bq  [col];
        else if (col < 576) v = bkv [col-192];
        else if (col < 720) v = bqp [col-576];
        else                v = bkvp[col-720];
        wcat[idx] = v;
    }
}

// ---------------------------------------------------------------------------
// k_proj: proj = s @ Wcat + bcat.  M=512,K=384,N=1152. 32x32 tiles, 64 thr,
// 4x4 register tile per thread, b128 LDS reads.
// ---------------------------------------------------------------------------
__global__ __launch_bounds__(64) void k_proj(
    const float* __restrict__ s, const float* __restrict__ wcat,
    float* __restrict__ proj)
{
    __shared__ float A[32*36];
    __shared__ float Bt[32*36];
    const int t  = threadIdx.x;
    const int ty = t >> 3, tx = t & 7;
    const int i0 = blockIdx.x * 32, c0 = blockIdx.y * 32;
    const float* bcat = wcat + 442368;

    float acc[4][4] = {};
    for (int k0 = 0; k0 < 384; k0 += 32) {
        __syncthreads();
        #pragma unroll
        for (int u = 0; u < 4; ++u) {
            const int q = t*4 + u;              // 0..255
            const int r = q >> 3, kk = (q & 7) * 4;
            *(float4*)&A[r*36 + kk] = *(const float4*)&s[(size_t)(i0+r)*384 + k0 + kk];
            const float4 wv = *(const float4*)&wcat[(size_t)(k0+r)*1152 + c0 + kk];
            Bt[(kk+0)*36 + r] = wv.x;
            Bt[(kk+1)*36 + r] = wv.y;
            Bt[(kk+2)*36 + r] = wv.z;
            Bt[(kk+3)*36 + r] = wv.w;
        }
        __syncthreads();
        #pragma unroll
        for (int k4 = 0; k4 < 32; k4 += 4) {
            float4 a4[4], b4[4];
            #pragma unroll
            for (int rr = 0; rr < 4; ++rr) a4[rr] = *(const float4*)&A [(rr*8+ty)*36 + k4];
            #pragma unroll
            for (int cc = 0; cc < 4; ++cc) b4[cc] = *(const float4*)&Bt[(cc*8+tx)*36 + k4];
            #pragma unroll
            for (int rr = 0; rr < 4; ++rr)
                #pragma unroll
                for (int cc = 0; cc < 4; ++cc)
                    acc[rr][cc] = fmaf(a4[rr].x, b4[cc].x,
                                  fmaf(a4[rr].y, b4[cc].y,
                                  fmaf(a4[rr].z, b4[cc].z,
                                  fmaf(a4[rr].w, b4[cc].w, acc[rr][cc]))));
        }
    }
    #pragma unroll
    for (int rr = 0; rr < 4; ++rr)
        #pragma unroll
        for (int cc = 0; cc < 4; ++cc) {
            const int c = c0 + cc*8 + tx;
            proj[(size_t)(i0 + rr*8 + ty)*NPROJ + c] = acc[rr][cc] + bcat[c];
        }
}

// ---------------------------------------------------------------------------
// k_rot: rotate/translate qp & kvp into global frame.
// ---------------------------------------------------------------------------
__global__ __launch_bounds__(192) void k_rot(
    const float* __restrict__ proj, const float* __restrict__ rots,
    const float* __restrict__ trans,
    float* __restrict__ qp_g, float* __restrict__ kp_g, float* __restrict__ vp_g)
{
    const int i = blockIdx.x;
    const int t = threadIdx.x;
    const float* R = rots  + (size_t)i * 9;
    const float* T = trans + (size_t)i * 3;
    const float* row = proj + (size_t)i * NPROJ;
    const float r00=R[0],r01=R[1],r02=R[2],r10=R[3],r11=R[4],r12=R[5],r20=R[6],r21=R[7],r22=R[8];
    const float t0=T[0], t1=T[1], t2=T[2];
    if (t < 48) {
        const int p = t;
        const float v0 = row[576 + p], v1 = row[576 + 48 + p], v2 = row[576 + 96 + p];
        float* dst = qp_g + (size_t)i*144 + p*3;
        dst[0] = r00*v0 + r01*v1 + r02*v2 + t0;
        dst[1] = r10*v0 + r11*v1 + r12*v2 + t1;
        dst[2] = r20*v0 + r21*v1 + r22*v2 + t2;
    } else {
        const int p = t - 48;
        const float v0 = row[720 + p], v1 = row[720 + 144 + p], v2 = row[720 + 288 + p];
        const float o0 = r00*v0 + r01*v1 + r02*v2 + t0;
        const float o1 = r10*v0 + r11*v1 + r12*v2 + t1;
        const float o2 = r20*v0 + r21*v1 + r22*v2 + t2;
        const int h = p / 12, pp = p % 12;
        if (pp < 4) {
            float* dst = kp_g + (size_t)i*144 + (h*4+pp)*3;
            dst[0]=o0; dst[1]=o1; dst[2]=o2;
        } else {
            float* dst = vp_g + (size_t)i*288 + (h*8+(pp-4))*3;
            dst[0]=o0; dst[1]=o1; dst[2]=o2;
        }
    }
}

// ---------------------------------------------------------------------------
// k_logit: fused z@Wb bias + qk + point-dist + mask -> pre-softmax logits.
// grid (512 i, 4 jq) x 256 thr: jj=t&127 (128 j per block), hb=(t>>7)*6.
// z staged through LDS in 8 double-buffered chunks of 16 c-columns via
// global_load_lds(16B): coalesced (16 lines/instr vs 64), zero VGPR cost.
// LDS float4-rotated layout via pre-swizzled SOURCE address (dest linear).
// ---------------------------------------------------------------------------
__global__ __launch_bounds__(256) void k_logit(
    const float* __restrict__ proj, const float* __restrict__ z,
    const float* __restrict__ mask,
    const float* __restrict__ Wb,  const float* __restrict__ bb,
    const float* __restrict__ head_w,
    const float* __restrict__ qp_g, const float* __restrict__ kp_g,
    float* __restrict__ a)
{
    const int i  = blockIdx.x, jq = blockIdx.y;
    const int t  = threadIdx.x;
    const int jj = t & 127, j = jq*128 + jj;
    const int j0 = jq*128;
    const int hb = __builtin_amdgcn_readfirstlane((t >> 7) * 6);  // wave-uniform

    __shared__ float qlds[336];          // [0,192)=q, [192,336)=qp
    __shared__ float zt[2][128*16];      // 2 x 8 KB chunk buffers

    for (int idx = t; idx < 336; idx += 256)
        qlds[idx] = (idx < 192) ? proj[(size_t)i*NPROJ + idx]
                                : qp_g[(size_t)i*144 + (idx-192)];

    const float SC_QK = 0.14433756729740643f;  // sqrt(1/48)
    const float SC_B  = 0.57735026918962576f;  // sqrt(1/3)
    const float SC_HW = 0.13608276348795434f;  // sqrt(1/54)

    float acc[6], hw[6];
    #pragma unroll
    for (int u = 0; u < 6; ++u) {
        acc[u] = bb[hb+u];
        hw[u]  = log1pf(expf(head_w[hb+u])) * SC_HW;
    }

    // ---- z chunk staging helper (as a lambda-free macro-ish block) ----
    // chunk ch covers c in [ch*16, ch*16+16). Per thread 2 issues (v=0,1):
    // gl = v*256+t; row = gl>>2; pos4 = gl&3; src f4 = (pos4 - row)&3.
    // LDS dest (linear) = zt[b] + gl*4 floats = row*16 + pos4*4.
    const size_t zrowbase = (size_t)i * N_RES + j0;
#define STAGE(b, ch) do {                                                     \
        _Pragma("unroll")                                                     \
        for (int v = 0; v < 2; ++v) {                                         \
            const int gl  = v*256 + t;                                        \
            const int row = gl >> 2;                                          \
            const int f4  = ((gl & 3) - row) & 3;                             \
            const float* gsrc = z + (zrowbase + row)*128 + (ch)*16 + f4*4;    \
            GLOAD_LDS16(gsrc, &zt[b][gl*4]);                                  \
        }                                                                     \
    } while (0)

    __syncthreads();            // qlds ready (and its loads retire first)

    STAGE(0, 0);
    #pragma unroll
    for (int ch = 0; ch < 8; ++ch) {
        const int cur = ch & 1;
        if (ch < 7) STAGE(cur ^ 1, ch + 1);
        if (ch < 7) asm volatile("s_waitcnt vmcnt(2)" ::: "memory");
        else        asm volatile("s_waitcnt vmcnt(0)" ::: "memory");
        __syncthreads();        // all waves' chunk segments in LDS
        #pragma unroll
        for (int cc4 = 0; cc4 < 4; ++cc4) {
            const float4 zv = *(const float4*)&zt[cur][jj*16 + (((cc4 + jj) & 3) << 2)];
            const float* wbc = Wb + (ch*16 + cc4*4)*12 + hb;   // s_loads (hb SGPR)
            #pragma unroll
            for (int u = 0; u < 6; ++u)
                acc[u] = fmaf(zv.x, wbc[u],
                         fmaf(zv.y, wbc[12+u],
                         fmaf(zv.z, wbc[24+u],
                         fmaf(zv.w, wbc[36+u], acc[u]))));
        }
        __syncthreads();        // reads done -> buffer may be overwritten
    }
#undef STAGE

    const float* kr  = proj + (size_t)j * NPROJ + 192;
    const float* kpr = kp_g + (size_t)j * 144;
    const float mterm = 100000.0f * (mask[i] * mask[j] - 1.0f);
    #pragma unroll
    for (int u = 0; u < 6; ++u) {
        const int h = hb + u;
        float qk = 0.f;
        #pragma unroll
        for (int c = 0; c < 16; c += 4) {
            const float4 k4 = *(const float4*)(kr + h*32 + c);
            qk = fmaf(qlds[h*16+c+0], k4.x,
                 fmaf(qlds[h*16+c+1], k4.y,
                 fmaf(qlds[h*16+c+2], k4.z,
                 fmaf(qlds[h*16+c+3], k4.w, qk))));
        }
        float s2 = 0.f;
        #pragma unroll
        for (int e = 0; e < 12; e += 4) {
            const float4 kp4 = *(const float4*)(kpr + h*12 + e);
            const float d0 = qlds[192 + h*12 + e+0] - kp4.x;
            const float d1 = qlds[192 + h*12 + e+1] - kp4.y;
            const float d2 = qlds[192 + h*12 + e+2] - kp4.z;
            const float d3 = qlds[192 + h*12 + e+3] - kp4.w;
            s2 += d0*d0 + d1*d1 + d2*d2 + d3*d3;
        }
        a[(size_t)i*6144 + h*512 + j] =
            fmaf(qk, SC_QK, fmaf(acc[u], SC_B, fmaf(-0.5f*hw[u], s2, mterm)));
    }
}

// ---------------------------------------------------------------------------
// k_softmax: one wave per (i,h) row of 512, in place.  6144 rows.
// ---------------------------------------------------------------------------
__global__ __launch_bounds__(256) void k_softmax(float* __restrict__ a)
{
    const int row  = blockIdx.x * 4 + (threadIdx.x >> 6);
    const int lane = threadIdx.x & 63;
    float* ar = a + (size_t)row * 512 + lane * 8;
    float4 v0 = *(const float4*)ar;
    float4 v1 = *(const float4*)(ar + 4);
    float m = fmaxf(fmaxf(fmaxf(v0.x,v0.y), fmaxf(v0.z,v0.w)),
                    fmaxf(fmaxf(v1.x,v1.y), fmaxf(v1.z,v1.w)));
    #pragma unroll
    for (int d = 1; d < 64; d <<= 1) m = fmaxf(m, __shfl_xor(m, d, 64));
    v0.x = expf(v0.x-m); v0.y = expf(v0.y-m); v0.z = expf(v0.z-m); v0.w = expf(v0.w-m);
    v1.x = expf(v1.x-m); v1.y = expf(v1.y-m); v1.z = expf(v1.z-m); v1.w = expf(v1.w-m);
    float ssum = v0.x+v0.y+v0.z+v0.w + v1.x+v1.y+v1.z+v1.w;
    #pragma unroll
    for (int d = 1; d < 64; d <<= 1) ssum += __shfl_xor(ssum, d, 64);
    const float inv = 1.f / ssum;
    v0.x*=inv; v0.y*=inv; v0.z*=inv; v0.w*=inv;
    v1.x*=inv; v1.y*=inv; v1.z*=inv; v1.w*=inv;
    *(float4*)ar = v0;
    *(float4*)(ar + 4) = v1;
}

// ---------------------------------------------------------------------------
// k_av: o and o_pt for TWO residues per block (shares V reads).
// ---------------------------------------------------------------------------
__global__ __launch_bounds__(512) void k_av(
    const float* __restrict__ a, const float* __restrict__ proj,
    const float* __restrict__ vp_g,
    const float* __restrict__ rots, const float* __restrict__ trans,
    float* __restrict__ cat)
{
    const int i0 = blockIdx.x * 2;
    const int t  = threadIdx.x;
    __shared__ float al[2*12*LSTR];
    __shared__ float opt_raw[2][288];

    #pragma unroll
    for (int p = 0; p < 6; ++p) {
        const int q4 = p*512 + t;            // < 3072 float4s
        const int el = q4 * 4;
        const int ii = el / 6144, rem = el % 6144;
        const int h = rem >> 9, jj = rem & 511;
        *(float4*)&al[(ii*12+h)*LSTR + jj] = *(const float4*)&a[(size_t)(i0+ii)*6144 + rem];
    }
    __syncthreads();

    float acc0 = 0.f, acc1 = 0.f;
    if (t < 480) {
        const int hh    = (t < 192) ? (t >> 4) : (t - 192) / 24;
        const int o_off = 192 + (t >> 4)*32 + 16 + (t & 15);
        const int vi    = t - 192;
        const float* al0 = al + hh*LSTR;
        const float* al1 = al + (12+hh)*LSTR;
        for (int j0 = 0; j0 < N_RES; j0 += 8) {
            const float4 a00 = *(const float4*)&al0[j0];
            const float4 a01 = *(const float4*)&al0[j0+4];
            const float4 a10 = *(const float4*)&al1[j0];
            const float4 a11 = *(const float4*)&al1[j0+4];
            float v[8];
            if (t < 192) {
                #pragma unroll
                for (int w = 0; w < 8; ++w) v[w] = proj[(size_t)(j0+w)*NPROJ + o_off];
            } else {
                #pragma unroll
                for (int w = 0; w < 8; ++w) v[w] = vp_g[(size_t)(j0+w)*288 + vi];
            }
            acc0 = fmaf(a00.x,v[0], fmaf(a00.y,v[1], fmaf(a00.z,v[2], fmaf(a00.w,v[3], acc0))));
            acc0 = fmaf(a01.x,v[4], fmaf(a01.y,v[5], fmaf(a01.z,v[6], fmaf(a01.w,v[7], acc0))));
            acc1 = fmaf(a10.x,v[0], fmaf(a10.y,v[1], fmaf(a10.z,v[2], fmaf(a10.w,v[3], acc1))));
            acc1 = fmaf(a11.x,v[4], fmaf(a11.y,v[5], fmaf(a11.z,v[6], fmaf(a11.w,v[7], acc1))));
        }
        if (t < 192) {
            cat[(size_t)i0*2112 + t]     = acc0;
            cat[(size_t)(i0+1)*2112 + t] = acc1;
        } else {
            opt_raw[0][vi] = acc0;
            opt_raw[1][vi] = acc1;
        }
    }
    __syncthreads();
    if (t < 192) {   // t<96: residue i0, else i0+1;  u = h*8+p
        const int sel = (t < 96) ? 0 : 1;
        const int u   = (t < 96) ? t : t - 96;
        const int i   = i0 + sel;
        const float* R = rots  + (size_t)i * 9;
        const float* T = trans + (size_t)i * 3;
        const float r0 = opt_raw[sel][u*3+0] - T[0];
        const float r1 = opt_raw[sel][u*3+1] - T[1];
        const float r2 = opt_raw[sel][u*3+2] - T[2];
        const float o0 = R[0]*r0 + R[3]*r1 + R[6]*r2;
        const float o1 = R[1]*r0 + R[4]*r1 + R[7]*r2;
        const float o2 = R[2]*r0 + R[5]*r1 + R[8]*r2;
        float* crow = cat + (size_t)i * 2112;
        crow[192 +   0 + u] = o0;
        crow[192 +  96 + u] = o1;
        crow[192 + 192 + u] = o2;
        crow[480 + u] = sqrtf(o0*o0 + o1*o1 + o2*o2 + 1e-8f);
    }
}

// ---------------------------------------------------------------------------
// k_opair: o_pair[i][h][c] = sum_j a[i][h][j] * z[i][j][c].
// 512 blocks x 512 thr (8 waves): c=t&127 (coalesced z), 3 heads per group.
// ---------------------------------------------------------------------------
__global__ __launch_bounds__(512) void k_opair(
    const float* __restrict__ a, const float* __restrict__ z,
    float* __restrict__ cat)
{
    const int i = blockIdx.x;
    const int t = threadIdx.x;
    __shared__ float al[12*LSTR];
    #pragma unroll
    for (int p = 0; p < 3; ++p) {
        const int q4 = p*512 + t;            // < 1536 float4s
        const int el = q4 * 4;
        const int h = el >> 9, jj = el & 511;
        *(float4*)&al[h*LSTR + jj] = *(const float4*)&a[(size_t)i*6144 + el];
    }
    __syncthreads();

    const int c  = t & 127;
    const int h0 = (t >> 7) * 3;
    const float* al0 = al + (h0+0)*LSTR;
    const float* al1 = al + (h0+1)*LSTR;
    const float* al2 = al + (h0+2)*LSTR;
    const float* zb  = z + (size_t)i*65536 + c;
    float acc0 = 0.f, acc1 = 0.f, acc2 = 0.f;
    for (int j0 = 0; j0 < N_RES; j0 += 4) {
        const float4 a0 = *(const float4*)&al0[j0];
        const float4 a1 = *(const float4*)&al1[j0];
        const float4 a2 = *(const float4*)&al2[j0];
        const float z0 = zb[(size_t)(j0+0)*128];
        const float z1 = zb[(size_t)(j0+1)*128];
        const float z2 = zb[(size_t)(j0+2)*128];
        const float z3 = zb[(size_t)(j0+3)*128];
        acc0 = fmaf(a0.x,z0, fmaf(a0.y,z1, fmaf(a0.z,z2, fmaf(a0.w,z3, acc0))));
        acc1 = fmaf(a1.x,z0, fmaf(a1.y,z1, fmaf(a1.z,z2, fmaf(a1.w,z3, acc1))));
        acc2 = fmaf(a2.x,z0, fmaf(a2.y,z1, fmaf(a2.z,z2, fmaf(a2.w,z3, acc2))));
    }
    float* crow = cat + (size_t)i * 2112 + 576;
    crow[(h0+0)*128 + c] = acc0;
    crow[(h0+1)*128 + c] = acc1;
    crow[(h0+2)*128 + c] = acc2;
}

// ---------------------------------------------------------------------------
// k_outp: split-K partials of cat @ Wout. K=2112=6x352.
// ---------------------------------------------------------------------------
__global__ __launch_bounds__(64) void k_outp(
    const float* __restrict__ cat, const float* __restrict__ Wout,
    float* __restrict__ outp)
{
    __shared__ float A[32*36];
    __shared__ float Bt[32*36];
    const int t  = threadIdx.x;
    const int ty = t >> 3, tx = t & 7;
    const int i0 = blockIdx.x * 32, n0 = blockIdx.y * 32;
    const int kq = blockIdx.z;

    float acc[4][4] = {};
    for (int kc = 0; kc < 11; ++kc) {
        const int kb = kq*352 + kc*32;
        __syncthreads();
        #pragma unroll
        for (int u = 0; u < 4; ++u) {
            const int q = t*4 + u;
            const int r = q >> 3, kk = (q & 7) * 4;
            *(float4*)&A[r*36 + kk] = *(const float4*)&cat[(size_t)(i0+r)*2112 + kb + kk];
            const float4 wv = *(const float4*)&Wout[(size_t)(kb+r)*384 + n0 + kk];
            Bt[(kk+0)*36 + r] = wv.x;
            Bt[(kk+1)*36 + r] = wv.y;
            Bt[(kk+2)*36 + r] = wv.z;
            Bt[(kk+3)*36 + r] = wv.w;
        }
        __syncthreads();
        #pragma unroll
        for (int k4 = 0; k4 < 32; k4 += 4) {
            float4 a4[4], b4[4];
            #pragma unroll
            for (int rr = 0; rr < 4; ++rr) a4[rr] = *(const float4*)&A [(rr*8+ty)*36 + k4];
            #pragma unroll
            for (int cc = 0; cc < 4; ++cc) b4[cc] = *(const float4*)&Bt[(cc*8+tx)*36 + k4];
            #pragma unroll
            for (int rr = 0; rr < 4; ++rr)
                #pragma unroll
                for (int cc = 0; cc < 4; ++cc)
                    acc[rr][cc] = fmaf(a4[rr].x, b4[cc].x,
                                  fmaf(a4[rr].y, b4[cc].y,
                                  fmaf(a4[rr].z, b4[cc].z,
                                  fmaf(a4[rr].w, b4[cc].w, acc[rr][cc]))));
        }
    }
    float* op = outp + (size_t)kq * 196608;
    #pragma unroll
    for (int rr = 0; rr < 4; ++rr)
        #pragma unroll
        for (int cc = 0; cc < 4; ++cc)
            op[(size_t)(i0 + rr*8 + ty)*384 + n0 + cc*8 + tx] = acc[rr][cc];
}

__global__ __launch_bounds__(256) void k_red(
    const float* __restrict__ outp, const float* __restrict__ bout,
    float* __restrict__ out)
{
    const int e = blockIdx.x * 256 + threadIdx.x;   // < 196608
    float v = bout[e % 384];
    #pragma unroll
    for (int q = 0; q < 6; ++q) v += outp[(size_t)q*196608 + e];
    out[e] = v;
}

// ---------------------------------------------------------------------------
extern "C" void kernel_launch(void* const* d_in, const int* in_sizes, int n_in,
                              void* d_out, int out_size, void* d_ws, size_t ws_size,
                              hipStream_t stream)
{
    const float* s      = (const float*)d_in[0];
    const float* z      = (const float*)d_in[1];
    const float* rots   = (const float*)d_in[2];
    const float* trans  = (const float*)d_in[3];
    const float* mask   = (const float*)d_in[4];
    const float* Wq     = (const float*)d_in[5];
    const float* bq     = (const float*)d_in[6];
    const float* Wkv    = (const float*)d_in[7];
    const float* bkv    = (const float*)d_in[8];
    const float* Wqp    = (const float*)d_in[9];
    const float* bqp    = (const float*)d_in[10];
    const float* Wkvp   = (const float*)d_in[11];
    const float* bkvp   = (const float*)d_in[12];
    const float* Wb     = (const float*)d_in[13];
    const float* bb     = (const float*)d_in[14];
    const float* head_w = (const float*)d_in[15];
    const float* Wout   = (const float*)d_in[16];
    const float* bout   = (const float*)d_in[17];
    float* out = (float*)d_out;

    float* ws    = (float*)d_ws;
    float* wcat  = ws;                      // 443520
    float* proj  = wcat  + 443520;          // 589824
    float* qp_g  = proj  + 589824;          // 73728
    float* kp_g  = qp_g  + 73728;           // 73728
    float* vp_g  = kp_g  + 73728;           // 147456
    float* abuf  = vp_g  + 147456;          // 3145728 (a; later aliased as outp)
    float* cat   = abuf  + 3145728;         // 1081344
    float* outp  = abuf;                    // 1179648 <= 3145728, abuf dead by k_outp

    k_wcat   <<<1733, 256, 0, stream>>>(Wq, bq, Wkv, bkv, Wqp, bqp, Wkvp, bkvp, wcat);
    k_proj   <<<dim3(16, 36), 64, 0, stream>>>(s, wcat, proj);
    k_rot    <<<512, 192, 0, stream>>>(proj, rots, trans, qp_g, kp_g, vp_g);
    k_logit  <<<dim3(512, 4), 256, 0, stream>>>(proj, z, mask, Wb, bb, head_w,
                                                qp_g, kp_g, abuf);
    k_softmax<<<1536, 256, 0, stream>>>(abuf);
    k_av     <<<256, 512, 0, stream>>>(abuf, proj, vp_g, rots, trans, cat);
    k_opair  <<<512, 512, 0, stream>>>(abuf, z, cat);
    k_outp   <<<dim3(16, 12, 6), 64, 0, stream>>>(cat, Wout, outp);
    k_red    <<<768, 256, 0, stream>>>(outp, bout, out);
}

// Round 6
// 224.879 us; speedup vs baseline: 1.0129x; 1.0129x over previous
//
#include <hip/hip_runtime.h>
#include <math.h>

#define N_RES 512
#define NPROJ 1152
#define LSTR  520
#define ZSTR  36    // LDS row stride (dwords) for 32-c z chunks: conflict-free

// ---------------------------------------------------------------------------
// k_wcat: concatenate projection weights into Wcat[384][1152] + bcat[1152].
// ---------------------------------------------------------------------------
__global__ __launch_bounds__(256) void k_wcat(
    const float* __restrict__ Wq,  const float* __restrict__ bq,
    const float* __restrict__ Wkv, const float* __restrict__ bkv,
    const float* __restrict__ Wqp, const float* __restrict__ bqp,
    const float* __restrict__ Wkvp,const float* __restrict__ bkvp,
    float* __restrict__ wcat)   // 442368 weights + 1152 bias
{
    const int idx = blockIdx.x * 256 + threadIdx.x;
    if (idx < 442368) {
        const int k = idx / 1152, col = idx % 1152;
        float v;
        if (col < 192)      v = Wq  [(size_t)k*192 + col];
        else if (col < 576) v = Wkv [(size_t)k*384 + col-192];
        else if (col < 720) v = Wqp [(size_t)k*144 + col-576];
        else                v = Wkvp[(size_t)k*432 + col-720];
        wcat[idx] = v;
    } else if (idx < 443520) {
        const int col = idx - 442368;
        float v;
        if (col < 192)      v = bq  [col];
        else if (col < 576) v = bkv [col-192];
        else if (col < 720) v = bqp [col-576];
        else                v = bkvp[col-720];
        wcat[idx] = v;
    }
}

// ---------------------------------------------------------------------------
// k_proj: proj = s @ Wcat + bcat.  M=512,K=384,N=1152. 32x32 tiles, 64 thr,
// 4x4 register tile per thread, b128 LDS reads.
// ---------------------------------------------------------------------------
__global__ __launch_bounds__(64) void k_proj(
    const float* __restrict__ s, const float* __restrict__ wcat,
    float* __restrict__ proj)
{
    __shared__ float A[32*36];
    __shared__ float Bt[32*36];
    const int t  = threadIdx.x;
    const int ty = t >> 3, tx = t & 7;
    const int i0 = blockIdx.x * 32, c0 = blockIdx.y * 32;
    const float* bcat = wcat + 442368;

    float acc[4][4] = {};
    for (int k0 = 0; k0 < 384; k0 += 32) {
        __syncthreads();
        #pragma unroll
        for (int u = 0; u < 4; ++u) {
            const int q = t*4 + u;              // 0..255
            const int r = q >> 3, kk = (q & 7) * 4;
            *(float4*)&A[r*36 + kk] = *(const float4*)&s[(size_t)(i0+r)*384 + k0 + kk];
            const float4 wv = *(const float4*)&wcat[(size_t)(k0+r)*1152 + c0 + kk];
            Bt[(kk+0)*36 + r] = wv.x;
            Bt[(kk+1)*36 + r] = wv.y;
            Bt[(kk+2)*36 + r] = wv.z;
            Bt[(kk+3)*36 + r] = wv.w;
        }
        __syncthreads();
        #pragma unroll
        for (int k4 = 0; k4 < 32; k4 += 4) {
            float4 a4[4], b4[4];
            #pragma unroll
            for (int rr = 0; rr < 4; ++rr) a4[rr] = *(const float4*)&A [(rr*8+ty)*36 + k4];
            #pragma unroll
            for (int cc = 0; cc < 4; ++cc) b4[cc] = *(const float4*)&Bt[(cc*8+tx)*36 + k4];
            #pragma unroll
            for (int rr = 0; rr < 4; ++rr)
                #pragma unroll
                for (int cc = 0; cc < 4; ++cc)
                    acc[rr][cc] = fmaf(a4[rr].x, b4[cc].x,
                                  fmaf(a4[rr].y, b4[cc].y,
                                  fmaf(a4[rr].z, b4[cc].z,
                                  fmaf(a4[rr].w, b4[cc].w, acc[rr][cc]))));
        }
    }
    #pragma unroll
    for (int rr = 0; rr < 4; ++rr)
        #pragma unroll
        for (int cc = 0; cc < 4; ++cc) {
            const int c = c0 + cc*8 + tx;
            proj[(size_t)(i0 + rr*8 + ty)*NPROJ + c] = acc[rr][cc] + bcat[c];
        }
}

// ---------------------------------------------------------------------------
// k_rot: rotate/translate qp & kvp into global frame.
// ---------------------------------------------------------------------------
__global__ __launch_bounds__(192) void k_rot(
    const float* __restrict__ proj, const float* __restrict__ rots,
    const float* __restrict__ trans,
    float* __restrict__ qp_g, float* __restrict__ kp_g, float* __restrict__ vp_g)
{
    const int i = blockIdx.x;
    const int t = threadIdx.x;
    const float* R = rots  + (size_t)i * 9;
    const float* T = trans + (size_t)i * 3;
    const float* row = proj + (size_t)i * NPROJ;
    const float r00=R[0],r01=R[1],r02=R[2],r10=R[3],r11=R[4],r12=R[5],r20=R[6],r21=R[7],r22=R[8];
    const float t0=T[0], t1=T[1], t2=T[2];
    if (t < 48) {
        const int p = t;
        const float v0 = row[576 + p], v1 = row[576 + 48 + p], v2 = row[576 + 96 + p];
        float* dst = qp_g + (size_t)i*144 + p*3;
        dst[0] = r00*v0 + r01*v1 + r02*v2 + t0;
        dst[1] = r10*v0 + r11*v1 + r12*v2 + t1;
        dst[2] = r20*v0 + r21*v1 + r22*v2 + t2;
    } else {
        const int p = t - 48;
        const float v0 = row[720 + p], v1 = row[720 + 144 + p], v2 = row[720 + 288 + p];
        const float o0 = r00*v0 + r01*v1 + r02*v2 + t0;
        const float o1 = r10*v0 + r11*v1 + r12*v2 + t1;
        const float o2 = r20*v0 + r21*v1 + r22*v2 + t2;
        const int h = p / 12, pp = p % 12;
        if (pp < 4) {
            float* dst = kp_g + (size_t)i*144 + (h*4+pp)*3;
            dst[0]=o0; dst[1]=o1; dst[2]=o2;
        } else {
            float* dst = vp_g + (size_t)i*288 + (h*8+(pp-4))*3;
            dst[0]=o0; dst[1]=o1; dst[2]=o2;
        }
    }
}

// ---------------------------------------------------------------------------
// k_logit: fused z@Wb bias + qk + point-dist + mask -> pre-softmax logits.
// grid (512 i, 4 jq) x 256 thr: jj=t&127, hb=(t>>7)*6 (6 heads per half).
// z staged via REG->LDS transpose-free padded tile: zt[128][ZSTR=36].
//   stage write b128 @ row*36+pos*4 : each bank 2x per 16-lane phase (free)
//   read  b128 @ jj*36 + cc*4      : banks tile 32, 2-way (free)
// Global side: 8 lanes/row -> every 64B line fully consumed per instruction.
// Double-buffered, next chunk's loads issued before compute.
// ---------------------------------------------------------------------------
__global__ __launch_bounds__(256) void k_logit(
    const float* __restrict__ proj, const float* __restrict__ z,
    const float* __restrict__ mask,
    const float* __restrict__ Wb,  const float* __restrict__ bb,
    const float* __restrict__ head_w,
    const float* __restrict__ qp_g, const float* __restrict__ kp_g,
    float* __restrict__ a)
{
    const int i  = blockIdx.x, jq = blockIdx.y;
    const int t  = threadIdx.x;
    const int jj = t & 127, j = jq*128 + jj;
    const int j0 = jq*128;
    const int hb = __builtin_amdgcn_readfirstlane((t >> 7) * 6);  // wave-uniform

    __shared__ float qlds[336];          // [0,192)=q, [192,336)=qp
    __shared__ float zt[2][128*ZSTR];    // 2 x 18 KB padded chunk buffers

    for (int idx = t; idx < 336; idx += 256)
        qlds[idx] = (idx < 192) ? proj[(size_t)i*NPROJ + idx]
                                : qp_g[(size_t)i*144 + (idx-192)];

    const float SC_QK = 0.14433756729740643f;  // sqrt(1/48)
    const float SC_B  = 0.57735026918962576f;  // sqrt(1/3)
    const float SC_HW = 0.13608276348795434f;  // sqrt(1/54)

    float acc[6], hw[6];
    #pragma unroll
    for (int u = 0; u < 6; ++u) {
        acc[u] = bb[hb+u];
        hw[u]  = log1pf(expf(head_w[hb+u])) * SC_HW;
    }

    // per-thread staging geometry: 4 float4s per 32-c chunk
    // v: row = v*32 + (t>>3), pos = t&7
    const int srow = t >> 3, spos = t & 7;
    const float* zb = z + ((size_t)i * N_RES + j0) * 128;
    float4 g[4];

#define LOADG(ch) do {                                                        \
        _Pragma("unroll")                                                     \
        for (int v = 0; v < 4; ++v)                                           \
            g[v] = *(const float4*)&zb[(size_t)(v*32 + srow)*128 +            \
                                       (ch)*32 + spos*4];                     \
    } while (0)
#define WRITEB(b) do {                                                        \
        _Pragma("unroll")                                                     \
        for (int v = 0; v < 4; ++v)                                           \
            *(float4*)&zt[b][(v*32 + srow)*ZSTR + spos*4] = g[v];             \
    } while (0)

    LOADG(0);
    WRITEB(0);
    __syncthreads();

    #pragma unroll
    for (int ch = 0; ch < 4; ++ch) {
        const int cur = ch & 1;
        if (ch < 3) LOADG(ch + 1);          // HBM latency hides under compute
        #pragma unroll
        for (int cc = 0; cc < 8; ++cc) {
            const float4 zv = *(const float4*)&zt[cur][jj*ZSTR + cc*4];
            const float* wbc = Wb + (ch*32 + cc*4)*12 + hb;   // s_loads
            #pragma unroll
            for (int u = 0; u < 6; ++u)
                acc[u] = fmaf(zv.x, wbc[u],
                         fmaf(zv.y, wbc[12+u],
                         fmaf(zv.z, wbc[24+u],
                         fmaf(zv.w, wbc[36+u], acc[u]))));
        }
        __syncthreads();                    // all waves done reading buf[cur]
        if (ch < 3) {
            WRITEB(cur ^ 1);
            __syncthreads();                // writes visible before next read
        }
    }
#undef LOADG
#undef WRITEB

    const float* kr  = proj + (size_t)j * NPROJ + 192;
    const float* kpr = kp_g + (size_t)j * 144;
    const float mterm = 100000.0f * (mask[i] * mask[j] - 1.0f);
    #pragma unroll
    for (int u = 0; u < 6; ++u) {
        const int h = hb + u;
        float qk = 0.f;
        #pragma unroll
        for (int c = 0; c < 16; c += 4) {
            const float4 k4 = *(const float4*)(kr + h*32 + c);
            qk = fmaf(qlds[h*16+c+0], k4.x,
                 fmaf(qlds[h*16+c+1], k4.y,
                 fmaf(qlds[h*16+c+2], k4.z,
                 fmaf(qlds[h*16+c+3], k4.w, qk))));
        }
        float s2 = 0.f;
        #pragma unroll
        for (int e = 0; e < 12; e += 4) {
            const float4 kp4 = *(const float4*)(kpr + h*12 + e);
            const float d0 = qlds[192 + h*12 + e+0] - kp4.x;
            const float d1 = qlds[192 + h*12 + e+1] - kp4.y;
            const float d2 = qlds[192 + h*12 + e+2] - kp4.z;
            const float d3 = qlds[192 + h*12 + e+3] - kp4.w;
            s2 += d0*d0 + d1*d1 + d2*d2 + d3*d3;
        }
        a[(size_t)i*6144 + h*512 + j] =
            fmaf(qk, SC_QK, fmaf(acc[u], SC_B, fmaf(-0.5f*hw[u], s2, mterm)));
    }
}

// ---------------------------------------------------------------------------
// k_softmax: one wave per (i,h) row of 512, in place.  6144 rows.
// ---------------------------------------------------------------------------
__global__ __launch_bounds__(256) void k_softmax(float* __restrict__ a)
{
    const int row  = blockIdx.x * 4 + (threadIdx.x >> 6);
    const int lane = threadIdx.x & 63;
    float* ar = a + (size_t)row * 512 + lane * 8;
    float4 v0 = *(const float4*)ar;
    float4 v1 = *(const float4*)(ar + 4);
    float m = fmaxf(fmaxf(fmaxf(v0.x,v0.y), fmaxf(v0.z,v0.w)),
                    fmaxf(fmaxf(v1.x,v1.y), fmaxf(v1.z,v1.w)));
    #pragma unroll
    for (int d = 1; d < 64; d <<= 1) m = fmaxf(m, __shfl_xor(m, d, 64));
    v0.x = expf(v0.x-m); v0.y = expf(v0.y-m); v0.z = expf(v0.z-m); v0.w = expf(v0.w-m);
    v1.x = expf(v1.x-m); v1.y = expf(v1.y-m); v1.z = expf(v1.z-m); v1.w = expf(v1.w-m);
    float ssum = v0.x+v0.y+v0.z+v0.w + v1.x+v1.y+v1.z+v1.w;
    #pragma unroll
    for (int d = 1; d < 64; d <<= 1) ssum += __shfl_xor(ssum, d, 64);
    const float inv = 1.f / ssum;
    v0.x*=inv; v0.y*=inv; v0.z*=inv; v0.w*=inv;
    v1.x*=inv; v1.y*=inv; v1.z*=inv; v1.w*=inv;
    *(float4*)ar = v0;
    *(float4*)(ar + 4) = v1;
}

// ---------------------------------------------------------------------------
// k_av: o and o_pt for TWO residues per block (shares V reads).
// ---------------------------------------------------------------------------
__global__ __launch_bounds__(512) void k_av(
    const float* __restrict__ a, const float* __restrict__ proj,
    const float* __restrict__ vp_g,
    const float* __restrict__ rots, const float* __restrict__ trans,
    float* __restrict__ cat)
{
    const int i0 = blockIdx.x * 2;
    const int t  = threadIdx.x;
    __shared__ float al[2*12*LSTR];
    __shared__ float opt_raw[2][288];

    #pragma unroll
    for (int p = 0; p < 6; ++p) {
        const int q4 = p*512 + t;            // < 3072 float4s
        const int el = q4 * 4;
        const int ii = el / 6144, rem = el % 6144;
        const int h = rem >> 9, jj = rem & 511;
        *(float4*)&al[(ii*12+h)*LSTR + jj] = *(const float4*)&a[(size_t)(i0+ii)*6144 + rem];
    }
    __syncthreads();

    float acc0 = 0.f, acc1 = 0.f;
    if (t < 480) {
        const int hh    = (t < 192) ? (t >> 4) : (t - 192) / 24;
        const int o_off = 192 + (t >> 4)*32 + 16 + (t & 15);
        const int vi    = t - 192;
        const float* al0 = al + hh*LSTR;
        const float* al1 = al + (12+hh)*LSTR;
        for (int j0 = 0; j0 < N_RES; j0 += 8) {
            const float4 a00 = *(const float4*)&al0[j0];
            const float4 a01 = *(const float4*)&al0[j0+4];
            const float4 a10 = *(const float4*)&al1[j0];
            const float4 a11 = *(const float4*)&al1[j0+4];
            float v[8];
            if (t < 192) {
                #pragma unroll
                for (int w = 0; w < 8; ++w) v[w] = proj[(size_t)(j0+w)*NPROJ + o_off];
            } else {
                #pragma unroll
                for (int w = 0; w < 8; ++w) v[w] = vp_g[(size_t)(j0+w)*288 + vi];
            }
            acc0 = fmaf(a00.x,v[0], fmaf(a00.y,v[1], fmaf(a00.z,v[2], fmaf(a00.w,v[3], acc0))));
            acc0 = fmaf(a01.x,v[4], fmaf(a01.y,v[5], fmaf(a01.z,v[6], fmaf(a01.w,v[7], acc0))));
            acc1 = fmaf(a10.x,v[0], fmaf(a10.y,v[1], fmaf(a10.z,v[2], fmaf(a10.w,v[3], acc1))));
            acc1 = fmaf(a11.x,v[4], fmaf(a11.y,v[5], fmaf(a11.z,v[6], fmaf(a11.w,v[7], acc1))));
        }
        if (t < 192) {
            cat[(size_t)i0*2112 + t]     = acc0;
            cat[(size_t)(i0+1)*2112 + t] = acc1;
        } else {
            opt_raw[0][vi] = acc0;
            opt_raw[1][vi] = acc1;
        }
    }
    __syncthreads();
    if (t < 192) {   // t<96: residue i0, else i0+1;  u = h*8+p
        const int sel = (t < 96) ? 0 : 1;
        const int u   = (t < 96) ? t : t - 96;
        const int i   = i0 + sel;
        const float* R = rots  + (size_t)i * 9;
        const float* T = trans + (size_t)i * 3;
        const float r0 = opt_raw[sel][u*3+0] - T[0];
        const float r1 = opt_raw[sel][u*3+1] - T[1];
        const float r2 = opt_raw[sel][u*3+2] - T[2];
        const float o0 = R[0]*r0 + R[3]*r1 + R[6]*r2;
        const float o1 = R[1]*r0 + R[4]*r1 + R[7]*r2;
        const float o2 = R[2]*r0 + R[5]*r1 + R[8]*r2;
        float* crow = cat + (size_t)i * 2112;
        crow[192 +   0 + u] = o0;
        crow[192 +  96 + u] = o1;
        crow[192 + 192 + u] = o2;
        crow[480 + u] = sqrtf(o0*o0 + o1*o1 + o2*o2 + 1e-8f);
    }
}

// ---------------------------------------------------------------------------
// k_opair: o_pair[i][h][c] = sum_j a[i][h][j] * z[i][j][c].
// 512 blocks x 512 thr (8 waves): c=t&127 (coalesced z), 3 heads per group.
// ---------------------------------------------------------------------------
__global__ __launch_bounds__(512) void k_opair(
    const float* __restrict__ a, const float* __restrict__ z,
    float* __restrict__ cat)
{
    const int i = blockIdx.x;
    const int t = threadIdx.x;
    __shared__ float al[12*LSTR];
    #pragma unroll
    for (int p = 0; p < 3; ++p) {
        const int q4 = p*512 + t;            // < 1536 float4s
        const int el = q4 * 4;
        const int h = el >> 9, jj = el & 511;
        *(float4*)&al[h*LSTR + jj] = *(const float4*)&a[(size_t)i*6144 + el];
    }
    __syncthreads();

    const int c  = t & 127;
    const int h0 = (t >> 7) * 3;
    const float* al0 = al + (h0+0)*LSTR;
    const float* al1 = al + (h0+1)*LSTR;
    const float* al2 = al + (h0+2)*LSTR;
    const float* zb  = z + (size_t)i*65536 + c;
    float acc0 = 0.f, acc1 = 0.f, acc2 = 0.f;
    for (int j0 = 0; j0 < N_RES; j0 += 4) {
        const float4 a0 = *(const float4*)&al0[j0];
        const float4 a1 = *(const float4*)&al1[j0];
        const float4 a2 = *(const float4*)&al2[j0];
        const float z0 = zb[(size_t)(j0+0)*128];
        const float z1 = zb[(size_t)(j0+1)*128];
        const float z2 = zb[(size_t)(j0+2)*128];
        const float z3 = zb[(size_t)(j0+3)*128];
        acc0 = fmaf(a0.x,z0, fmaf(a0.y,z1, fmaf(a0.z,z2, fmaf(a0.w,z3, acc0))));
        acc1 = fmaf(a1.x,z0, fmaf(a1.y,z1, fmaf(a1.z,z2, fmaf(a1.w,z3, acc1))));
        acc2 = fmaf(a2.x,z0, fmaf(a2.y,z1, fmaf(a2.z,z2, fmaf(a2.w,z3, acc2))));
    }
    float* crow = cat + (size_t)i * 2112 + 576;
    crow[(h0+0)*128 + c] = acc0;
    crow[(h0+1)*128 + c] = acc1;
    crow[(h0+2)*128 + c] = acc2;
}

// ---------------------------------------------------------------------------
// k_outp: split-K partials of cat @ Wout. K=2112=6x352.
// ---------------------------------------------------------------------------
__global__ __launch_bounds__(64) void k_outp(
    const float* __restrict__ cat, const float* __restrict__ Wout,
    float* __restrict__ outp)
{
    __shared__ float A[32*36];
    __shared__ float Bt[32*36];
    const int t  = threadIdx.x;
    const int ty = t >> 3, tx = t & 7;
    const int i0 = blockIdx.x * 32, n0 = blockIdx.y * 32;
    const int kq = blockIdx.z;

    float acc[4][4] = {};
    for (int kc = 0; kc < 11; ++kc) {
        const int kb = kq*352 + kc*32;
        __syncthreads();
        #pragma unroll
        for (int u = 0; u < 4; ++u) {
            const int q = t*4 + u;
            const int r = q >> 3, kk = (q & 7) * 4;
            *(float4*)&A[r*36 + kk] = *(const float4*)&cat[(size_t)(i0+r)*2112 + kb + kk];
            const float4 wv = *(const float4*)&Wout[(size_t)(kb+r)*384 + n0 + kk];
            Bt[(kk+0)*36 + r] = wv.x;
            Bt[(kk+1)*36 + r] = wv.y;
            Bt[(kk+2)*36 + r] = wv.z;
            Bt[(kk+3)*36 + r] = wv.w;
        }
        __syncthreads();
        #pragma unroll
        for (int k4 = 0; k4 < 32; k4 += 4) {
            float4 a4[4], b4[4];
            #pragma unroll
            for (int rr = 0; rr < 4; ++rr) a4[rr] = *(const float4*)&A [(rr*8+ty)*36 + k4];
            #pragma unroll
            for (int cc = 0; cc < 4; ++cc) b4[cc] = *(const float4*)&Bt[(cc*8+tx)*36 + k4];
            #pragma unroll
            for (int rr = 0; rr < 4; ++rr)
                #pragma unroll
                for (int cc = 0; cc < 4; ++cc)
                    acc[rr][cc] = fmaf(a4[rr].x, b4[cc].x,
                                  fmaf(a4[rr].y, b4[cc].y,
                                  fmaf(a4[rr].z, b4[cc].z,
                                  fmaf(a4[rr].w, b4[cc].w, acc[rr][cc]))));
        }
    }
    float* op = outp + (size_t)kq * 196608;
    #pragma unroll
    for (int rr = 0; rr < 4; ++rr)
        #pragma unroll
        for (int cc = 0; cc < 4; ++cc)
            op[(size_t)(i0 + rr*8 + ty)*384 + n0 + cc*8 + tx] = acc[rr][cc];
}

__global__ __launch_bounds__(256) void k_red(
    const float* __restrict__ outp, const float* __restrict__ bout,
    float* __restrict__ out)
{
    const int e = blockIdx.x * 256 + threadIdx.x;   // < 196608
    float v = bout[e % 384];
    #pragma unroll
    for (int q = 0; q < 6; ++q) v += outp[(size_t)q*196608 + e];
    out[e] = v;
}

// ---------------------------------------------------------------------------
extern "C" void kernel_launch(void* const* d_in, const int* in_sizes, int n_in,
                              void* d_out, int out_size, void* d_ws, size_t ws_size,
                              hipStream_t stream)
{
    const float* s      = (const float*)d_in[0];
    const float* z      = (const float*)d_in[1];
    const float* rots   = (const float*)d_in[2];
    const float* trans  = (const float*)d_in[3];
    const float* mask   = (const float*)d_in[4];
    const float* Wq     = (const float*)d_in[5];
    const float* bq     = (const float*)d_in[6];
    const float* Wkv    = (const float*)d_in[7];
    const float* bkv    = (const float*)d_in[8];
    const float* Wqp    = (const float*)d_in[9];
    const float* bqp    = (const float*)d_in[10];
    const float* Wkvp   = (const float*)d_in[11];
    const float* bkvp   = (const float*)d_in[12];
    const float* Wb     = (const float*)d_in[13];
    const float* bb     = (const float*)d_in[14];
    const float* head_w = (const float*)d_in[15];
    const float* Wout   = (const float*)d_in[16];
    const float* bout   = (const float*)d_in[17];
    float* out = (float*)d_out;

    float* ws    = (float*)d_ws;
    float* wcat  = ws;                      // 443520
    float* proj  = wcat  + 443520;          // 589824
    float* qp_g  = proj  + 589824;          // 73728
    float* kp_g  = qp_g  + 73728;           // 73728
    float* vp_g  = kp_g  + 73728;           // 147456
    float* abuf  = vp_g  + 147456;          // 3145728 (a; later aliased as outp)
    float* cat   = abuf  + 3145728;         // 1081344
    float* outp  = abuf;                    // 1179648 <= 3145728, abuf dead by k_outp

    k_wcat   <<<1733, 256, 0, stream>>>(Wq, bq, Wkv, bkv, Wqp, bqp, Wkvp, bkvp, wcat);
    k_proj   <<<dim3(16, 36), 64, 0, stream>>>(s, wcat, proj);
    k_rot    <<<512, 192, 0, stream>>>(proj, rots, trans, qp_g, kp_g, vp_g);
    k_logit  <<<dim3(512, 4), 256, 0, stream>>>(proj, z, mask, Wb, bb, head_w,
                                                qp_g, kp_g, abuf);
    k_softmax<<<1536, 256, 0, stream>>>(abuf);
    k_av     <<<256, 512, 0, stream>>>(abuf, proj, vp_g, rots, trans, cat);
    k_opair  <<<512, 512, 0, stream>>>(abuf, z, cat);
    k_outp   <<<dim3(16, 12, 6), 64, 0, stream>>>(cat, Wout, outp);
    k_red    <<<768, 256, 0, stream>>>(outp, bout, out);
}

// Round 7
// 180.877 us; speedup vs baseline: 1.2593x; 1.2433x over previous
//
#include <hip/hip_runtime.h>
#include <math.h>

#define N_RES 512
#define NPROJ 1152
#define LSTR  520

#define SC_QK 0.14433756729740643f   // sqrt(1/48)
#define SC_B  0.57735026918962576f   // sqrt(1/3)
#define SC_HW 0.13608276348795434f   // sqrt(1/54)

// ---------------------------------------------------------------------------
// k_wcat: Wcat[384][1152] + bcat[1152] + WbT[12][128].
// ---------------------------------------------------------------------------
__global__ __launch_bounds__(256) void k_wcat(
    const float* __restrict__ Wq,  const float* __restrict__ bq,
    const float* __restrict__ Wkv, const float* __restrict__ bkv,
    const float* __restrict__ Wqp, const float* __restrict__ bqp,
    const float* __restrict__ Wkvp,const float* __restrict__ bkvp,
    const float* __restrict__ Wb,
    float* __restrict__ wcat)   // 442368 W + 1152 bias + 1536 WbT
{
    const int idx = blockIdx.x * 256 + threadIdx.x;
    if (idx < 442368) {
        const int k = idx / 1152, col = idx % 1152;
        float v;
        if (col < 192)      v = Wq  [(size_t)k*192 + col];
        else if (col < 576) v = Wkv [(size_t)k*384 + col-192];
        else if (col < 720) v = Wqp [(size_t)k*144 + col-576];
        else                v = Wkvp[(size_t)k*432 + col-720];
        wcat[idx] = v;
    } else if (idx < 443520) {
        const int col = idx - 442368;
        float v;
        if (col < 192)      v = bq  [col];
        else if (col < 576) v = bkv [col-192];
        else if (col < 720) v = bqp [col-576];
        else                v = bkvp[col-720];
        wcat[idx] = v;
    } else if (idx < 445056) {
        const int r = idx - 443520;          // WbT[h][c] = Wb[c][h]
        const int h = r >> 7, c = r & 127;
        wcat[idx] = Wb[c*12 + h];
    }
}

// ---------------------------------------------------------------------------
// k_proj: proj = s @ Wcat + bcat; also writes kT[h*16+c][j] transposed copy
// of the K columns (cols 192..576 with (col-192)&31 < 16).
// ---------------------------------------------------------------------------
__global__ __launch_bounds__(64) void k_proj(
    const float* __restrict__ s, const float* __restrict__ wcat,
    float* __restrict__ proj, float* __restrict__ kT)
{
    __shared__ float A[32*36];
    __shared__ float Bt[32*36];
    const int t  = threadIdx.x;
    const int ty = t >> 3, tx = t & 7;
    const int i0 = blockIdx.x * 32, c0 = blockIdx.y * 32;
    const float* bcat = wcat + 442368;

    float acc[4][4] = {};
    for (int k0 = 0; k0 < 384; k0 += 32) {
        __syncthreads();
        #pragma unroll
        for (int u = 0; u < 4; ++u) {
            const int q = t*4 + u;
            const int r = q >> 3, kk = (q & 7) * 4;
            *(float4*)&A[r*36 + kk] = *(const float4*)&s[(size_t)(i0+r)*384 + k0 + kk];
            const float4 wv = *(const float4*)&wcat[(size_t)(k0+r)*1152 + c0 + kk];
            Bt[(kk+0)*36 + r] = wv.x;
            Bt[(kk+1)*36 + r] = wv.y;
            Bt[(kk+2)*36 + r] = wv.z;
            Bt[(kk+3)*36 + r] = wv.w;
        }
        __syncthreads();
        #pragma unroll
        for (int k4 = 0; k4 < 32; k4 += 4) {
            float4 a4[4], b4[4];
            #pragma unroll
            for (int rr = 0; rr < 4; ++rr) a4[rr] = *(const float4*)&A [(rr*8+ty)*36 + k4];
            #pragma unroll
            for (int cc = 0; cc < 4; ++cc) b4[cc] = *(const float4*)&Bt[(cc*8+tx)*36 + k4];
            #pragma unroll
            for (int rr = 0; rr < 4; ++rr)
                #pragma unroll
                for (int cc = 0; cc < 4; ++cc)
                    acc[rr][cc] = fmaf(a4[rr].x, b4[cc].x,
                                  fmaf(a4[rr].y, b4[cc].y,
                                  fmaf(a4[rr].z, b4[cc].z,
                                  fmaf(a4[rr].w, b4[cc].w, acc[rr][cc]))));
        }
    }
    #pragma unroll
    for (int rr = 0; rr < 4; ++rr)
        #pragma unroll
        for (int cc = 0; cc < 4; ++cc) {
            const int c = c0 + cc*8 + tx;
            const int row = i0 + rr*8 + ty;
            const float val = acc[rr][cc] + bcat[c];
            proj[(size_t)row*NPROJ + c] = val;
            if (c >= 192 && c < 576) {
                const int w = (c - 192) & 31;
                if (w < 16)
                    kT[(size_t)((((c-192) >> 5) << 4) + w)*512 + row] = val;
            }
        }
}

// ---------------------------------------------------------------------------
// k_rot: rotate/translate qp & kvp. kp now written TRANSPOSED: kpT[h*12+e][i].
// ---------------------------------------------------------------------------
__global__ __launch_bounds__(192) void k_rot(
    const float* __restrict__ proj, const float* __restrict__ rots,
    const float* __restrict__ trans,
    float* __restrict__ qp_g, float* __restrict__ kpT, float* __restrict__ vp_g)
{
    const int i = blockIdx.x;
    const int t = threadIdx.x;
    const float* R = rots  + (size_t)i * 9;
    const float* T = trans + (size_t)i * 3;
    const float* row = proj + (size_t)i * NPROJ;
    const float r00=R[0],r01=R[1],r02=R[2],r10=R[3],r11=R[4],r12=R[5],r20=R[6],r21=R[7],r22=R[8];
    const float t0=T[0], t1=T[1], t2=T[2];
    if (t < 48) {
        const int p = t;
        const float v0 = row[576 + p], v1 = row[576 + 48 + p], v2 = row[576 + 96 + p];
        float* dst = qp_g + (size_t)i*144 + p*3;
        dst[0] = r00*v0 + r01*v1 + r02*v2 + t0;
        dst[1] = r10*v0 + r11*v1 + r12*v2 + t1;
        dst[2] = r20*v0 + r21*v1 + r22*v2 + t2;
    } else {
        const int p = t - 48;
        const float v0 = row[720 + p], v1 = row[720 + 144 + p], v2 = row[720 + 288 + p];
        const float o0 = r00*v0 + r01*v1 + r02*v2 + t0;
        const float o1 = r10*v0 + r11*v1 + r12*v2 + t1;
        const float o2 = r20*v0 + r21*v1 + r22*v2 + t2;
        const int h = p / 12, pp = p % 12;
        if (pp < 4) {
            const int e = (h*4 + pp)*3;          // = h*12 + pp*3
            kpT[(size_t)(e+0)*512 + i] = o0;
            kpT[(size_t)(e+1)*512 + i] = o1;
            kpT[(size_t)(e+2)*512 + i] = o2;
        } else {
            float* dst = vp_g + (size_t)i*288 + (h*8+(pp-4))*3;
            dst[0]=o0; dst[1]=o1; dst[2]=o2;
        }
    }
}

// ---------------------------------------------------------------------------
// k_logit: fused bias(z@Wb) + qk + point-dist + mask, block=(i, 64 j's).
// Phase 1: lane=(hg,cs,rp): WbT slice in 12 float4 REGISTERS (no s_load
//   chain), z coalesced, partial acc per (row,head,c-slice).
// Phase 2: c-slice reduction via padded LDS.
// Phase 3: lane=(j,hgrp): qk/point via kT/kpT coalesced along j.
// ---------------------------------------------------------------------------
__global__ __launch_bounds__(256) void k_logit(
    const float* __restrict__ proj, const float* __restrict__ z,
    const float* __restrict__ mask,
    const float* __restrict__ wbt,  const float* __restrict__ bb,
    const float* __restrict__ head_w,
    const float* __restrict__ qp_g, const float* __restrict__ kT,
    const float* __restrict__ kpT,
    float* __restrict__ a)
{
    const int i  = blockIdx.x, jq = blockIdx.y;   // jq 0..7
    const int t  = threadIdx.x;
    const int j0 = jq * 64;

    __shared__ float qlds[336];       // [0,192)=q, [192,336)=qp
    __shared__ float red[64 * 108];   // [row][h*9 + cs], pad 9
    __shared__ float biasr[64 * 13];  // [row][h], pad 13

    for (int idx = t; idx < 336; idx += 256)
        qlds[idx] = (idx < 192) ? proj[(size_t)i*NPROJ + idx]
                                : qp_g[(size_t)i*144 + (idx-192)];

    // ---- phase 1: partial bias sums ----
    const int wv = t >> 6, l = t & 63;
    const int hg = l >> 4;          // 0..3 -> heads hg*3..hg*3+2
    const int cs = (l >> 1) & 7;    // 0..7 -> c in [cs*16, cs*16+16)
    const int rp = l & 1;
    const int rowbase = wv*16 + rp*8;

    float4 wb4[3][4];
    #pragma unroll
    for (int u = 0; u < 3; ++u)
        #pragma unroll
        for (int v = 0; v < 4; ++v)
            wb4[u][v] = *(const float4*)&wbt[(hg*3+u)*128 + cs*16 + v*4];

    const float* zbase = z + ((size_t)i*N_RES + j0 + rowbase)*128 + cs*16;
    float acc[8][3];
    #pragma unroll
    for (int rr = 0; rr < 8; ++rr) {
        float4 zv[4];
        #pragma unroll
        for (int v = 0; v < 4; ++v)
            zv[v] = *(const float4*)&zbase[(size_t)rr*128 + v*4];
        #pragma unroll
        for (int u = 0; u < 3; ++u) {
            float s = 0.f;
            #pragma unroll
            for (int v = 0; v < 4; ++v)
                s = fmaf(zv[v].x, wb4[u][v].x,
                    fmaf(zv[v].y, wb4[u][v].y,
                    fmaf(zv[v].z, wb4[u][v].z,
                    fmaf(zv[v].w, wb4[u][v].w, s))));
            acc[rr][u] = s;
        }
    }
    #pragma unroll
    for (int rr = 0; rr < 8; ++rr)
        #pragma unroll
        for (int u = 0; u < 3; ++u)
            red[(rowbase+rr)*108 + (hg*3+u)*9 + cs] = acc[rr][u];
    __syncthreads();

    // ---- phase 2: reduce the 8 c-slices ----
    #pragma unroll
    for (int q = 0; q < 3; ++q) {
        const int o = q*256 + t;          // 0..767 = row*12 + h
        const int row = o / 12, h = o % 12;
        float s = 0.f;
        #pragma unroll
        for (int k = 0; k < 8; ++k) s += red[row*108 + h*9 + k];
        biasr[row*13 + h] = s;
    }
    __syncthreads();

    // ---- phase 3: logits via kT/kpT (coalesced along j) ----
    const int j = t & 63, gj = j0 + j;
    const int hgrp = t >> 6;              // heads hgrp*3..hgrp*3+2
    const float mterm = 100000.0f * (mask[i]*mask[gj] - 1.0f);
    #pragma unroll
    for (int u = 0; u < 3; ++u) {
        const int h = hgrp*3 + u;
        const float hw = log1pf(expf(head_w[h])) * SC_HW;
        float qk = 0.f;
        #pragma unroll
        for (int c = 0; c < 16; ++c)
            qk = fmaf(qlds[h*16+c], kT[(size_t)(h*16+c)*512 + gj], qk);
        float s2 = 0.f;
        #pragma unroll
        for (int e = 0; e < 12; ++e) {
            const float d = qlds[192 + h*12 + e] - kpT[(size_t)(h*12+e)*512 + gj];
            s2 = fmaf(d, d, s2);
        }
        a[(size_t)i*6144 + h*512 + gj] =
            fmaf(qk, SC_QK,
            fmaf(biasr[j*13+h] + bb[h], SC_B,
            fmaf(-0.5f*hw, s2, mterm)));
    }
}

// ---------------------------------------------------------------------------
// k_softmax: one wave per (i,h) row of 512, in place.  6144 rows.
// ---------------------------------------------------------------------------
__global__ __launch_bounds__(256) void k_softmax(float* __restrict__ a)
{
    const int row  = blockIdx.x * 4 + (threadIdx.x >> 6);
    const int lane = threadIdx.x & 63;
    float* ar = a + (size_t)row * 512 + lane * 8;
    float4 v0 = *(const float4*)ar;
    float4 v1 = *(const float4*)(ar + 4);
    float m = fmaxf(fmaxf(fmaxf(v0.x,v0.y), fmaxf(v0.z,v0.w)),
                    fmaxf(fmaxf(v1.x,v1.y), fmaxf(v1.z,v1.w)));
    #pragma unroll
    for (int d = 1; d < 64; d <<= 1) m = fmaxf(m, __shfl_xor(m, d, 64));
    v0.x = expf(v0.x-m); v0.y = expf(v0.y-m); v0.z = expf(v0.z-m); v0.w = expf(v0.w-m);
    v1.x = expf(v1.x-m); v1.y = expf(v1.y-m); v1.z = expf(v1.z-m); v1.w = expf(v1.w-m);
    float ssum = v0.x+v0.y+v0.z+v0.w + v1.x+v1.y+v1.z+v1.w;
    #pragma unroll
    for (int d = 1; d < 64; d <<= 1) ssum += __shfl_xor(ssum, d, 64);
    const float inv = 1.f / ssum;
    v0.x*=inv; v0.y*=inv; v0.z*=inv; v0.w*=inv;
    v1.x*=inv; v1.y*=inv; v1.z*=inv; v1.w*=inv;
    *(float4*)ar = v0;
    *(float4*)(ar + 4) = v1;
}

// ---------------------------------------------------------------------------
// k_av: o and o_pt for TWO residues per block (shares V reads).
// ---------------------------------------------------------------------------
__global__ __launch_bounds__(512) void k_av(
    const float* __restrict__ a, const float* __restrict__ proj,
    const float* __restrict__ vp_g,
    const float* __restrict__ rots, const float* __restrict__ trans,
    float* __restrict__ cat)
{
    const int i0 = blockIdx.x * 2;
    const int t  = threadIdx.x;
    __shared__ float al[2*12*LSTR];
    __shared__ float opt_raw[2][288];

    #pragma unroll
    for (int p = 0; p < 6; ++p) {
        const int q4 = p*512 + t;
        const int el = q4 * 4;
        const int ii = el / 6144, rem = el % 6144;
        const int h = rem >> 9, jj = rem & 511;
        *(float4*)&al[(ii*12+h)*LSTR + jj] = *(const float4*)&a[(size_t)(i0+ii)*6144 + rem];
    }
    __syncthreads();

    float acc0 = 0.f, acc1 = 0.f;
    if (t < 480) {
        const int hh    = (t < 192) ? (t >> 4) : (t - 192) / 24;
        const int o_off = 192 + (t >> 4)*32 + 16 + (t & 15);
        const int vi    = t - 192;
        const float* al0 = al + hh*LSTR;
        const float* al1 = al + (12+hh)*LSTR;
        for (int j0 = 0; j0 < N_RES; j0 += 8) {
            const float4 a00 = *(const float4*)&al0[j0];
            const float4 a01 = *(const float4*)&al0[j0+4];
            const float4 a10 = *(const float4*)&al1[j0];
            const float4 a11 = *(const float4*)&al1[j0+4];
            float v[8];
            if (t < 192) {
                #pragma unroll
                for (int w = 0; w < 8; ++w) v[w] = proj[(size_t)(j0+w)*NPROJ + o_off];
            } else {
                #pragma unroll
                for (int w = 0; w < 8; ++w) v[w] = vp_g[(size_t)(j0+w)*288 + vi];
            }
            acc0 = fmaf(a00.x,v[0], fmaf(a00.y,v[1], fmaf(a00.z,v[2], fmaf(a00.w,v[3], acc0))));
            acc0 = fmaf(a01.x,v[4], fmaf(a01.y,v[5], fmaf(a01.z,v[6], fmaf(a01.w,v[7], acc0))));
            acc1 = fmaf(a10.x,v[0], fmaf(a10.y,v[1], fmaf(a10.z,v[2], fmaf(a10.w,v[3], acc1))));
            acc1 = fmaf(a11.x,v[4], fmaf(a11.y,v[5], fmaf(a11.z,v[6], fmaf(a11.w,v[7], acc1))));
        }
        if (t < 192) {
            cat[(size_t)i0*2112 + t]     = acc0;
            cat[(size_t)(i0+1)*2112 + t] = acc1;
        } else {
            opt_raw[0][vi] = acc0;
            opt_raw[1][vi] = acc1;
        }
    }
    __syncthreads();
    if (t < 192) {
        const int sel = (t < 96) ? 0 : 1;
        const int u   = (t < 96) ? t : t - 96;
        const int i   = i0 + sel;
        const float* R = rots  + (size_t)i * 9;
        const float* T = trans + (size_t)i * 3;
        const float r0 = opt_raw[sel][u*3+0] - T[0];
        const float r1 = opt_raw[sel][u*3+1] - T[1];
        const float r2 = opt_raw[sel][u*3+2] - T[2];
        const float o0 = R[0]*r0 + R[3]*r1 + R[6]*r2;
        const float o1 = R[1]*r0 + R[4]*r1 + R[7]*r2;
        const float o2 = R[2]*r0 + R[5]*r1 + R[8]*r2;
        float* crow = cat + (size_t)i * 2112;
        crow[192 +   0 + u] = o0;
        crow[192 +  96 + u] = o1;
        crow[192 + 192 + u] = o2;
        crow[480 + u] = sqrtf(o0*o0 + o1*o1 + o2*o2 + 1e-8f);
    }
}

// ---------------------------------------------------------------------------
// k_opair: o_pair[i][h][c] = sum_j a[i][h][j] * z[i][j][c].
// ---------------------------------------------------------------------------
__global__ __launch_bounds__(512) void k_opair(
    const float* __restrict__ a, const float* __restrict__ z,
    float* __restrict__ cat)
{
    const int i = blockIdx.x;
    const int t = threadIdx.x;
    __shared__ float al[12*LSTR];
    #pragma unroll
    for (int p = 0; p < 3; ++p) {
        const int q4 = p*512 + t;
        const int el = q4 * 4;
        const int h = el >> 9, jj = el & 511;
        *(float4*)&al[h*LSTR + jj] = *(const float4*)&a[(size_t)i*6144 + el];
    }
    __syncthreads();

    const int c  = t & 127;
    const int h0 = (t >> 7) * 3;
    const float* al0 = al + (h0+0)*LSTR;
    const float* al1 = al + (h0+1)*LSTR;
    const float* al2 = al + (h0+2)*LSTR;
    const float* zb  = z + (size_t)i*65536 + c;
    float acc0 = 0.f, acc1 = 0.f, acc2 = 0.f;
    for (int j0 = 0; j0 < N_RES; j0 += 4) {
        const float4 a0 = *(const float4*)&al0[j0];
        const float4 a1 = *(const float4*)&al1[j0];
        const float4 a2 = *(const float4*)&al2[j0];
        const float z0 = zb[(size_t)(j0+0)*128];
        const float z1 = zb[(size_t)(j0+1)*128];
        const float z2 = zb[(size_t)(j0+2)*128];
        const float z3 = zb[(size_t)(j0+3)*128];
        acc0 = fmaf(a0.x,z0, fmaf(a0.y,z1, fmaf(a0.z,z2, fmaf(a0.w,z3, acc0))));
        acc1 = fmaf(a1.x,z0, fmaf(a1.y,z1, fmaf(a1.z,z2, fmaf(a1.w,z3, acc1))));
        acc2 = fmaf(a2.x,z0, fmaf(a2.y,z1, fmaf(a2.z,z2, fmaf(a2.w,z3, acc2))));
    }
    float* crow = cat + (size_t)i * 2112 + 576;
    crow[(h0+0)*128 + c] = acc0;
    crow[(h0+1)*128 + c] = acc1;
    crow[(h0+2)*128 + c] = acc2;
}

// ---------------------------------------------------------------------------
// k_outp: split-K partials of cat @ Wout. K=2112=6x352.
// ---------------------------------------------------------------------------
__global__ __launch_bounds__(64) void k_outp(
    const float* __restrict__ cat, const float* __restrict__ Wout,
    float* __restrict__ outp)
{
    __shared__ float A[32*36];
    __shared__ float Bt[32*36];
    const int t  = threadIdx.x;
    const int ty = t >> 3, tx = t & 7;
    const int i0 = blockIdx.x * 32, n0 = blockIdx.y * 32;
    const int kq = blockIdx.z;

    float acc[4][4] = {};
    for (int kc = 0; kc < 11; ++kc) {
        const int kb = kq*352 + kc*32;
        __syncthreads();
        #pragma unroll
        for (int u = 0; u < 4; ++u) {
            const int q = t*4 + u;
            const int r = q >> 3, kk = (q & 7) * 4;
            *(float4*)&A[r*36 + kk] = *(const float4*)&cat[(size_t)(i0+r)*2112 + kb + kk];
            const float4 wv = *(const float4*)&Wout[(size_t)(kb+r)*384 + n0 + kk];
            Bt[(kk+0)*36 + r] = wv.x;
            Bt[(kk+1)*36 + r] = wv.y;
            Bt[(kk+2)*36 + r] = wv.z;
            Bt[(kk+3)*36 + r] = wv.w;
        }
        __syncthreads();
        #pragma unroll
        for (int k4 = 0; k4 < 32; k4 += 4) {
            float4 a4[4], b4[4];
            #pragma unroll
            for (int rr = 0; rr < 4; ++rr) a4[rr] = *(const float4*)&A [(rr*8+ty)*36 + k4];
            #pragma unroll
            for (int cc = 0; cc < 4; ++cc) b4[cc] = *(const float4*)&Bt[(cc*8+tx)*36 + k4];
            #pragma unroll
            for (int rr = 0; rr < 4; ++rr)
                #pragma unroll
                for (int cc = 0; cc < 4; ++cc)
                    acc[rr][cc] = fmaf(a4[rr].x, b4[cc].x,
                                  fmaf(a4[rr].y, b4[cc].y,
                                  fmaf(a4[rr].z, b4[cc].z,
                                  fmaf(a4[rr].w, b4[cc].w, acc[rr][cc]))));
        }
    }
    float* op = outp + (size_t)kq * 196608;
    #pragma unroll
    for (int rr = 0; rr < 4; ++rr)
        #pragma unroll
        for (int cc = 0; cc < 4; ++cc)
            op[(size_t)(i0 + rr*8 + ty)*384 + n0 + cc*8 + tx] = acc[rr][cc];
}

__global__ __launch_bounds__(256) void k_red(
    const float* __restrict__ outp, const float* __restrict__ bout,
    float* __restrict__ out)
{
    const int e = blockIdx.x * 256 + threadIdx.x;
    float v = bout[e % 384];
    #pragma unroll
    for (int q = 0; q < 6; ++q) v += outp[(size_t)q*196608 + e];
    out[e] = v;
}

// ---------------------------------------------------------------------------
extern "C" void kernel_launch(void* const* d_in, const int* in_sizes, int n_in,
                              void* d_out, int out_size, void* d_ws, size_t ws_size,
                              hipStream_t stream)
{
    const float* s      = (const float*)d_in[0];
    const float* z      = (const float*)d_in[1];
    const float* rots   = (const float*)d_in[2];
    const float* trans  = (const float*)d_in[3];
    const float* mask   = (const float*)d_in[4];
    const float* Wq     = (const float*)d_in[5];
    const float* bq     = (const float*)d_in[6];
    const float* Wkv    = (const float*)d_in[7];
    const float* bkv    = (const float*)d_in[8];
    const float* Wqp    = (const float*)d_in[9];
    const float* bqp    = (const float*)d_in[10];
    const float* Wkvp   = (const float*)d_in[11];
    const float* bkvp   = (const float*)d_in[12];
    const float* Wb     = (const float*)d_in[13];
    const float* bb     = (const float*)d_in[14];
    const float* head_w = (const float*)d_in[15];
    const float* Wout   = (const float*)d_in[16];
    const float* bout   = (const float*)d_in[17];
    float* out = (float*)d_out;

    float* ws    = (float*)d_ws;
    float* wcat  = ws;                      // 445056 (W 442368 + b 1152 + WbT 1536)
    float* wbt   = wcat  + 443520;          // alias inside wcat region
    float* proj  = wcat  + 445056;          // 589824
    float* qp_g  = proj  + 589824;          // 73728
    float* kpT   = qp_g  + 73728;           // 73728  [h*12+e][512]
    float* vp_g  = kpT   + 73728;           // 147456
    float* kT    = vp_g  + 147456;          // 98304  [h*16+c][512]
    float* abuf  = kT    + 98304;           // 3145728 (a; later aliased as outp)
    float* cat   = abuf  + 3145728;         // 1081344
    float* outp  = abuf;                    // 1179648 <= 3145728

    k_wcat   <<<1739, 256, 0, stream>>>(Wq, bq, Wkv, bkv, Wqp, bqp, Wkvp, bkvp, Wb, wcat);
    k_proj   <<<dim3(16, 36), 64, 0, stream>>>(s, wcat, proj, kT);
    k_rot    <<<512, 192, 0, stream>>>(proj, rots, trans, qp_g, kpT, vp_g);
    k_logit  <<<dim3(512, 8), 256, 0, stream>>>(proj, z, mask, wbt, bb, head_w,
                                                qp_g, kT, kpT, abuf);
    k_softmax<<<1536, 256, 0, stream>>>(abuf);
    k_av     <<<256, 512, 0, stream>>>(abuf, proj, vp_g, rots, trans, cat);
    k_opair  <<<512, 512, 0, stream>>>(abuf, z, cat);
    k_outp   <<<dim3(16, 12, 6), 64, 0, stream>>>(cat, Wout, outp);
    k_red    <<<768, 256, 0, stream>>>(outp, bout, out);
}